// Round 5
// baseline (1986.983 us; speedup 1.0000x reference)
//
#include <hip/hip_runtime.h>
#include <hip/hip_bf16.h>
#include <stdint.h>

#define BB   2
#define CC   256
#define NN   32768
#define DD   4
#define HH   256
#define WW   256
#define HWC  65536
#define NGG  3

typedef __attribute__((ext_vector_type(8))) short short8;
typedef __attribute__((ext_vector_type(4))) short short4v;
typedef __attribute__((ext_vector_type(4))) float f32x4;

// swizzled LDS index for a [64][256] bf16 tile: 16B-unit XOR by (row&7)
#define LXW(n, c) (((n) << 8) + ((((c) >> 3) ^ ((n) & 7)) << 3) + ((c) & 7))

__device__ __forceinline__ short f2bf(float f){
  union { float f; uint32_t u; } v; v.f = f;
  uint32_t u = v.u;
  uint32_t r = (u + 0x7fffu + ((u >> 16) & 1u)) >> 16;
  return (short)r;
}
__device__ __forceinline__ float bf2f(short s){
  union { uint32_t u; float f; } v; v.u = ((uint32_t)(uint16_t)s) << 16;
  return v.f;
}

// ---------------- counts / weights ----------------
__global__ __launch_bounds__(256) void count_kernel(const int* cell_ind, const float* occ, float* counts){
  int idx = blockIdx.x * 256 + threadIdx.x;      // over B*NG*N
  int n  = idx & (NN - 1);
  int bg = idx >> 15;                            // b*NG+g
  int b  = bg / NGG;
  atomicAdd(&counts[(size_t)bg * HWC + cell_ind[idx]], occ[(size_t)b * NN + n]);
}

__global__ __launch_bounds__(256) void weight_kernel(const int* cell_ind, const float* occ,
                                                     const float* counts, float* wts){
  int idx = blockIdx.x * 256 + threadIdx.x;
  int n  = idx & (NN - 1);
  int bg = idx >> 15;
  int b  = bg / NGG;
  float o = occ[(size_t)b * NN + n];
  float cnt = counts[(size_t)bg * HWC + cell_ind[idx]];
  wts[idx] = o / (cnt * o + 1e-6f);
}

// ---------------- BN stats (full pass; layer-0 sm only) ----------------
__global__ __launch_bounds__(256) void bnstats_kernel(const float* tok, const float* gamma,
                                                      const float* beta, float* sOut, float* tOut){
  int c = blockIdx.x;
  int t = threadIdx.x;
  float s = 0.f, sq = 0.f;
  for(int b = 0; b < BB; b++){
    const float4* p = (const float4*)(tok + ((size_t)b * CC + c) * NN);
    for(int i = t; i < NN / 4; i += 256){
      float4 v = p[i];
      s  += v.x + v.y + v.z + v.w;
      sq += v.x * v.x + v.y * v.y + v.z * v.z + v.w * v.w;
    }
  }
  __shared__ float rs[256], rq[256];
  rs[t] = s; rq[t] = sq;
  __syncthreads();
  for(int off = 128; off > 0; off >>= 1){
    if(t < off){ rs[t] += rs[t + off]; rq[t] += rq[t + off]; }
    __syncthreads();
  }
  if(t == 0){
    float m    = rs[0] / (float)(BB * NN);
    float var  = rq[0] / (float)(BB * NN) - m * m;
    float rstd = rsqrtf(var + 1e-5f);
    float g = gamma[c];
    sOut[c] = rstd * g;
    tOut[c] = beta[c] - m * rstd * g;
  }
}

// ---------------- finalize moments -> scale/bias, and zero the moment buffer ----------------
__global__ __launch_bounds__(256) void finalize_kernel(float* mom, const float* gamma, const float* beta,
                                                       float* sOut, float* tOut){
  int c = threadIdx.x;
  const float inv = 1.f / (float)(BB * NN);
  float m   = mom[c] * inv;
  float var = mom[256 + c] * inv - m * m;
  float rstd = rsqrtf(var + 1e-5f);
  float g = gamma[c];
  sOut[c] = rstd * g;
  tOut[c] = beta[c] - m * rstd * g;
  mom[c] = 0.f;
  mom[256 + c] = 0.f;
}

// ---------------- scatter (normalize + weight + atomic into grid) ----------------
__global__ __launch_bounds__(256) void scatter_kernel(const float* tok, const int* cell_ind,
                                                      const float* wts, const float* sA, const float* tA,
                                                      float* gridA, int g){
  int blk = blockIdx.x;                 // B*N/64
  int b   = blk >> 9;
  int n0  = (blk & 511) << 6;
  int t   = threadIdx.x;
  __shared__ float lds[256 * 65];
  __shared__ int   cellL[64];
  __shared__ float wL[64];
  if(t < 64){
    cellL[t] = cell_ind[((size_t)b * NGG + g) * NN + n0 + t];
    wL[t]    = wts[((size_t)b * NGG + g) * NN + n0 + t];
  }
  // stage + normalize: lds[c][p], p = point within 64
  int pf = (t & 15) * 4;
  for(int i = 0; i < 16; i++){
    int c = (t >> 4) + 16 * i;
    float s  = sA[c];
    float tt = tA[c];
    float4 v = *(const float4*)(tok + ((size_t)b * CC + c) * NN + n0 + pf);
    lds[c * 65 + pf + 0] = v.x * s + tt;
    lds[c * 65 + pf + 1] = v.y * s + tt;
    lds[c * 65 + pf + 2] = v.z * s + tt;
    lds[c * 65 + pf + 3] = v.w * s + tt;
  }
  __syncthreads();
  for(int p = 0; p < 64; p++){
    int   cell = cellL[p];
    float wp   = wL[p];
    atomicAdd(&gridA[((size_t)b * HWC + cell) * CC + t], lds[t * 65 + p] * wp);
  }
}

// ---------------- fused dwconv1 + relu + dwconv2, register rolling window, no LDS ----------------
__global__ __launch_bounds__(256) void conv_kernel(const float* __restrict__ gridA,
                                                   const float* __restrict__ k1, const float* __restrict__ b1,
                                                   const float* __restrict__ k2, const float* __restrict__ b2,
                                                   short* __restrict__ gridB){
  int bi = blockIdx.x;                  // b*1024 + ty*32 + tx
  int tx = bi & 31;
  int ty = (bi >> 5) & 31;
  int b  = bi >> 10;
  int c  = threadIdx.x;                 // 0..255 : one channel per thread
  int x0 = tx * 8, y0 = ty * 8;

  float w1r[9], w2r[9];
  #pragma unroll
  for(int i = 0; i < 9; i++){
    w1r[i] = k1[(size_t)c * 9 + i];
    w2r[i] = k2[(size_t)c * 9 + i];
  }
  float bb1 = b1[c], bb2 = b2[c];

  const float* gb = gridA + (size_t)b * HWC * CC + c;
  short*       ob = gridB + (size_t)b * HWC * CC + c;

  float in[3][12];                      // rolling 3 input rows (12 wide, halo 2)
  float mid[3][10];                     // rolling 3 mid rows (10 wide, halo 1)

  auto loadrow = [&](int slot, int yy){
    #pragma unroll
    for(int j = 0; j < 12; j++){
      int xx = x0 - 2 + j;
      float v = 0.f;
      if(yy >= 0 && yy < HH && xx >= 0 && xx < WW)
        v = gb[((size_t)yy * WW + xx) * CC];
      in[slot][j] = v;
    }
  };
  loadrow(0, y0 - 2);
  loadrow(1, y0 - 1);

  #pragma unroll
  for(int r = 0; r < 10; r++){
    loadrow((r + 2) % 3, y0 + r);
    int ym = y0 - 1 + r;
    int s0 = r % 3, s1 = (r + 1) % 3, s2 = (r + 2) % 3;
    bool yok = (ym >= 0) && (ym < HH);
    #pragma unroll
    for(int mx = 0; mx < 10; mx++){
      int xg = x0 - 1 + mx;
      float a = bb1;
      #pragma unroll
      for(int kx = 0; kx < 3; kx++){
        a += in[s0][mx + kx] * w1r[0 * 3 + kx];
        a += in[s1][mx + kx] * w1r[1 * 3 + kx];
        a += in[s2][mx + kx] * w1r[2 * 3 + kx];
      }
      float v = fmaxf(a, 0.f);
      if(!yok || xg < 0 || xg >= WW) v = 0.f;   // conv2 SAME-pads with 0 outside image
      mid[r % 3][mx] = v;
    }
    if(r >= 2){
      int oy = r - 2;
      int m0 = (r - 2) % 3, m1 = (r - 1) % 3, m2 = r % 3;
      #pragma unroll
      for(int ox = 0; ox < 8; ox++){
        float a = bb2;
        #pragma unroll
        for(int kx = 0; kx < 3; kx++){
          a += mid[m0][ox + kx] * w2r[0 * 3 + kx];
          a += mid[m1][ox + kx] * w2r[1 * 3 + kx];
          a += mid[m2][ox + kx] * w2r[2 * 3 + kx];
        }
        ob[((size_t)(y0 + oy) * WW + (x0 + ox)) * CC] = f2bf(a);
      }
    }
  }
}

// ---------------- gather + residual (+ cm BN moment accumulation) ----------------
__global__ __launch_bounds__(256) void gather_kernel(const float* tokIn, float* tokOut, const short* gridB,
                                                     const int* cell_ind, const float* occ,
                                                     const float* smScale, int g, float* cmMom){
  int blk = blockIdx.x;
  int b   = blk >> 9;
  int n0  = (blk & 511) << 6;
  int t   = threadIdx.x;
  __shared__ float lds[256 * 65];
  __shared__ int   cellL[64];
  __shared__ float occL[64];
  if(t < 64){
    cellL[t] = cell_ind[((size_t)b * NGG + g) * NN + n0 + t];
    occL[t]  = occ[(size_t)b * NN + n0 + t];
  }
  __syncthreads();
  int half = t >> 7;
  int ch   = (t & 127) * 2;
  for(int it = 0; it < 32; it++){
    int p = it * 2 + half;
    int cell = cellL[p];
    uint32_t u = *(const uint32_t*)&gridB[((size_t)b * HWC + cell) * CC + ch];
    lds[ch * 65 + p]       = bf2f((short)(u & 0xffff));
    lds[(ch + 1) * 65 + p] = bf2f((short)(u >> 16));
  }
  __syncthreads();
  int pf = (t & 15) * 4;
  int j  = t & 15;
  for(int i = 0; i < 16; i++){
    int c = (t >> 4) + 16 * i;
    float sc = smScale[c];
    size_t addr = ((size_t)b * CC + c) * NN + n0 + pf;
    float4 tv = *(const float4*)(tokIn + addr);
    float4 o;
    o.x = tv.x + sc * (occL[pf + 0] * lds[c * 65 + pf + 0]);
    o.y = tv.y + sc * (occL[pf + 1] * lds[c * 65 + pf + 1]);
    o.z = tv.z + sc * (occL[pf + 2] * lds[c * 65 + pf + 2]);
    o.w = tv.w + sc * (occL[pf + 3] * lds[c * 65 + pf + 3]);
    *(float4*)(tokOut + addr) = o;
    // cm BN moments: reduce over the 16 lanes sharing channel c
    float s1 = o.x + o.y + o.z + o.w;
    float s2 = o.x * o.x + o.y * o.y + o.z * o.z + o.w * o.w;
    s1 += __shfl_xor(s1, 1);  s2 += __shfl_xor(s2, 1);
    s1 += __shfl_xor(s1, 2);  s2 += __shfl_xor(s2, 2);
    s1 += __shfl_xor(s1, 4);  s2 += __shfl_xor(s2, 4);
    s1 += __shfl_xor(s1, 8);  s2 += __shfl_xor(s2, 8);
    if(j == (i & 15)){
      atomicAdd(&cmMom[c], s1);
      atomicAdd(&cmMom[256 + c], s2);
    }
  }
}

// ---------------- fold BN into W1/b1, convert W2 ----------------
__global__ __launch_bounds__(256) void fold_kernel(const float* w1, const float* bias1, const float* w2,
                                                   const float* sB, const float* tB,
                                                   short* W1f, short* W2f, float* b1f){
  int o = blockIdx.x;
  int t = threadIdx.x;
  float w = w1[(size_t)o * CC + t];
  W1f[o * CC + t] = f2bf(w * sB[t]);
  W2f[o * CC + t] = f2bf(w2[(size_t)o * CC + t]);
  __shared__ float red[256];
  red[t] = w * tB[t];
  __syncthreads();
  for(int off = 128; off > 0; off >>= 1){
    if(t < off) red[t] += red[t + off];
    __syncthreads();
  }
  if(t == 0) b1f[o] = bias1[o] + red[0];
}

// ---------------- fused MLP (+ sm BN moment accumulation for next layer) ----------------
__global__ __launch_bounds__(256) void mlp_kernel(float* tok, const short* W1f, const float* b1f,
                                                  const short* W2f, const float* b2, const float* sc2,
                                                  float* smMom){
  int blk = blockIdx.x;                  // B * N/64
  int b   = blk >> 9;
  int n0  = (blk & 511) << 6;
  int t   = threadIdx.x;
  int w   = t >> 6;
  int l   = t & 63;
  __shared__ short lds[64 * 256];        // swizzled; X tile, then reused for H tile
  float* tb = tok + (size_t)b * CC * NN;

  // stage X tile (64 tokens x 256 channels), transpose 4x4 in regs
  {
    int nb = t & 15;
    int cbq = t >> 4;
    for(int i = 0; i < 4; i++){
      int c0 = cbq * 4 + 64 * i;
      float4 v0 = *(const float4*)(tb + (size_t)(c0 + 0) * NN + n0 + nb * 4);
      float4 v1 = *(const float4*)(tb + (size_t)(c0 + 1) * NN + n0 + nb * 4);
      float4 v2 = *(const float4*)(tb + (size_t)(c0 + 2) * NN + n0 + nb * 4);
      float4 v3 = *(const float4*)(tb + (size_t)(c0 + 3) * NN + n0 + nb * 4);
      short4v s0 = { f2bf(v0.x), f2bf(v1.x), f2bf(v2.x), f2bf(v3.x) };
      short4v s1 = { f2bf(v0.y), f2bf(v1.y), f2bf(v2.y), f2bf(v3.y) };
      short4v s2 = { f2bf(v0.z), f2bf(v1.z), f2bf(v2.z), f2bf(v3.z) };
      short4v s3 = { f2bf(v0.w), f2bf(v1.w), f2bf(v2.w), f2bf(v3.w) };
      *(short4v*)&lds[LXW(nb * 4 + 0, c0)] = s0;
      *(short4v*)&lds[LXW(nb * 4 + 1, c0)] = s1;
      *(short4v*)&lds[LXW(nb * 4 + 2, c0)] = s2;
      *(short4v*)&lds[LXW(nb * 4 + 3, c0)] = s3;
    }
  }
  __syncthreads();

  int ob = w * 64;
  int lr = l & 15;
  int lq = l >> 4;

  f32x4 acc[4][4];
  for(int m = 0; m < 4; m++)
    for(int nf = 0; nf < 4; nf++)
      acc[m][nf] = (f32x4){0.f, 0.f, 0.f, 0.f};
  for(int kk = 0; kk < 8; kk++){
    int kb = kk * 32 + lq * 8;
    short8 af[4], bfr[4];
    for(int m = 0; m < 4; m++)
      af[m] = *(const short8*)&W1f[(size_t)(ob + m * 16 + lr) * CC + kb];
    for(int nf = 0; nf < 4; nf++)
      bfr[nf] = *(const short8*)&lds[LXW(nf * 16 + lr, kb)];
    for(int m = 0; m < 4; m++)
      for(int nf = 0; nf < 4; nf++)
        acc[m][nf] = __builtin_amdgcn_mfma_f32_16x16x32_bf16(af[m], bfr[nf], acc[m][nf], 0, 0, 0);
  }
  __syncthreads();                       // all X reads done before H overwrites the buffer

  // epilogue 1: + b1', relu, bf16 -> lds (H tile, [n][o] swizzled)
  for(int m = 0; m < 4; m++){
    int o0 = ob + m * 16 + lq * 4;
    float bb0 = b1f[o0], bb1 = b1f[o0 + 1], bb2 = b1f[o0 + 2], bb3 = b1f[o0 + 3];
    for(int nf = 0; nf < 4; nf++){
      int n = nf * 16 + lr;
      short4v hv = { f2bf(fmaxf(acc[m][nf][0] + bb0, 0.f)),
                     f2bf(fmaxf(acc[m][nf][1] + bb1, 0.f)),
                     f2bf(fmaxf(acc[m][nf][2] + bb2, 0.f)),
                     f2bf(fmaxf(acc[m][nf][3] + bb3, 0.f)) };
      *(short4v*)&lds[LXW(n, o0)] = hv;
    }
  }
  __syncthreads();

  f32x4 acc2[4][4];
  for(int m = 0; m < 4; m++)
    for(int nf = 0; nf < 4; nf++)
      acc2[m][nf] = (f32x4){0.f, 0.f, 0.f, 0.f};
  for(int kk = 0; kk < 8; kk++){
    int kb = kk * 32 + lq * 8;
    short8 af[4], bfr[4];
    for(int m = 0; m < 4; m++)
      af[m] = *(const short8*)&W2f[(size_t)(ob + m * 16 + lr) * CC + kb];
    for(int nf = 0; nf < 4; nf++)
      bfr[nf] = *(const short8*)&lds[LXW(nf * 16 + lr, kb)];
    for(int m = 0; m < 4; m++)
      for(int nf = 0; nf < 4; nf++)
        acc2[m][nf] = __builtin_amdgcn_mfma_f32_16x16x32_bf16(af[m], bfr[nf], acc2[m][nf], 0, 0, 0);
  }
  // epilogue 2: tok += sc2*(acc2 + b2); accumulate sm BN moments of the values written
  for(int m = 0; m < 4; m++){
    int o0 = ob + m * 16 + lq * 4;
    for(int r = 0; r < 4; r++){
      int o = o0 + r;
      float s  = sc2[o];
      float bb = b2[o];
      float s1 = 0.f, s2 = 0.f;
      for(int nf = 0; nf < 4; nf++){
        int n = nf * 16 + lr;
        size_t addr = (size_t)o * NN + n0 + n;
        float v = tb[addr] + s * (acc2[m][nf][r] + bb);
        tb[addr] = v;
        s1 += v;
        s2 += v * v;
      }
      s1 += __shfl_xor(s1, 1);  s2 += __shfl_xor(s2, 1);
      s1 += __shfl_xor(s1, 2);  s2 += __shfl_xor(s2, 2);
      s1 += __shfl_xor(s1, 4);  s2 += __shfl_xor(s2, 4);
      s1 += __shfl_xor(s1, 8);  s2 += __shfl_xor(s2, 8);
      if(lr == m * 4 + r){
        atomicAdd(&smMom[o], s1);
        atomicAdd(&smMom[256 + o], s2);
      }
    }
  }
}

extern "C" void kernel_launch(void* const* d_in, const int* in_sizes, int n_in,
                              void* d_out, int out_size, void* d_ws, size_t ws_size,
                              hipStream_t stream) {
  const float* tokens   = (const float*)d_in[0];
  const int*   cell_ind = (const int*)d_in[1];
  const float* occ      = (const float*)d_in[2];
  const float* cm_gamma = (const float*)d_in[3];
  const float* cm_beta  = (const float*)d_in[4];
  const float* cm_w1    = (const float*)d_in[5];
  const float* cm_b1    = (const float*)d_in[6];
  const float* cm_w2    = (const float*)d_in[7];
  const float* cm_b2    = (const float*)d_in[8];
  const float* cm_scale = (const float*)d_in[9];
  const float* sm_gamma = (const float*)d_in[10];
  const float* sm_beta  = (const float*)d_in[11];
  const float* sm_k1    = (const float*)d_in[12];
  const float* sm_b1    = (const float*)d_in[13];
  const float* sm_k2    = (const float*)d_in[14];
  const float* sm_b2    = (const float*)d_in[15];
  const float* sm_scale = (const float*)d_in[16];
  float* out = (float*)d_out;
  (void)in_sizes; (void)n_in; (void)out_size; (void)ws_size;

  char* ws = (char*)d_ws;
  size_t off = 0;
  auto carve = [&](size_t bytes) -> void* {
    void* p = ws + off;
    off = (off + bytes + 255) & ~(size_t)255;
    return p;
  };
  float* counts = (float*)carve((size_t)BB * NGG * HWC * 4);   // 1.5 MB
  float* smMom  = (float*)carve(512 * 4);                      // contiguous with counts
  float* cmMom  = (float*)carve(512 * 4);
  float* wts    = (float*)carve((size_t)BB * NGG * NN * 4);
  float* sA  = (float*)carve(CC * 4);
  float* tA  = (float*)carve(CC * 4);
  float* sB  = (float*)carve(CC * 4);
  float* tB  = (float*)carve(CC * 4);
  float* b1f = (float*)carve(CC * 4);
  short* W1f = (short*)carve((size_t)CC * CC * 2);
  short* W2f = (short*)carve((size_t)CC * CC * 2);
  float* gridA = (float*)carve((size_t)BB * HWC * CC * 4);
  short* gridB = (short*)carve((size_t)BB * HWC * CC * 2);

  // zero counts + both moment buffers in one memset (they are carved contiguously)
  hipMemsetAsync(counts, 0, (size_t)BB * NGG * HWC * 4 + 2 * 256 * 4 + 512 * 4 + 512 * 4, stream);
  count_kernel<<<BB * NGG * NN / 256, 256, 0, stream>>>(cell_ind, occ, counts);
  weight_kernel<<<BB * NGG * NN / 256, 256, 0, stream>>>(cell_ind, occ, counts, wts);

  const float* tokCur = tokens;
  for(int d = 0; d < DD; d++){
    int g = d % NGG;
    if(d == 0)
      bnstats_kernel<<<CC, 256, 0, stream>>>(tokCur, sm_gamma, sm_beta, sA, tA);
    else
      finalize_kernel<<<1, 256, 0, stream>>>(smMom, sm_gamma + d * CC, sm_beta + d * CC, sA, tA);
    hipMemsetAsync(gridA, 0, (size_t)BB * HWC * CC * 4, stream);
    scatter_kernel<<<BB * NN / 64, 256, 0, stream>>>(tokCur, cell_ind, wts, sA, tA, gridA, g);
    conv_kernel<<<BB * 32 * 32, 256, 0, stream>>>(gridA, sm_k1 + (size_t)d * CC * 9, sm_b1 + d * CC,
                                                  sm_k2 + (size_t)d * CC * 9, sm_b2 + d * CC, gridB);
    gather_kernel<<<BB * NN / 64, 256, 0, stream>>>(tokCur, out, gridB, cell_ind, occ,
                                                    sm_scale + d * CC, g, cmMom);
    finalize_kernel<<<1, 256, 0, stream>>>(cmMom, cm_gamma + d * CC, cm_beta + d * CC, sB, tB);
    fold_kernel<<<CC, 256, 0, stream>>>(cm_w1 + (size_t)d * CC * CC, cm_b1 + d * CC,
                                        cm_w2 + (size_t)d * CC * CC, sB, tB, W1f, W2f, b1f);
    mlp_kernel<<<BB * NN / 64, 256, 0, stream>>>(out, W1f, b1f, W2f, cm_b2 + d * CC,
                                                 cm_scale + d * CC, smMom);
    tokCur = out;
  }
}

// Round 6
// 1174.795 us; speedup vs baseline: 1.6913x; 1.6913x over previous
//
#include <hip/hip_runtime.h>
#include <hip/hip_bf16.h>
#include <stdint.h>

#define BB   2
#define CC   256
#define NN   32768
#define DD   4
#define HH   256
#define WW   256
#define HWC  65536
#define NGG  3
#define NSLOT 64

typedef __attribute__((ext_vector_type(8))) short short8;
typedef __attribute__((ext_vector_type(4))) short short4v;
typedef __attribute__((ext_vector_type(4))) float f32x4;

// swizzled LDS index for a [64][256] bf16 tile: 16B-unit XOR by (row&7)
#define LXW(n, c) (((n) << 8) + ((((c) >> 3) ^ ((n) & 7)) << 3) + ((c) & 7))

__device__ __forceinline__ short f2bf(float f){
  union { float f; uint32_t u; } v; v.f = f;
  uint32_t u = v.u;
  uint32_t r = (u + 0x7fffu + ((u >> 16) & 1u)) >> 16;
  return (short)r;
}
__device__ __forceinline__ float bf2f(short s){
  union { uint32_t u; float f; } v; v.u = ((uint32_t)(uint16_t)s) << 16;
  return v.f;
}

// ---------------- counts / weights ----------------
__global__ __launch_bounds__(256) void count_kernel(const int* cell_ind, const float* occ, float* counts){
  int idx = blockIdx.x * 256 + threadIdx.x;      // over B*NG*N
  int n  = idx & (NN - 1);
  int bg = idx >> 15;                            // b*NG+g
  int b  = bg / NGG;
  atomicAdd(&counts[(size_t)bg * HWC + cell_ind[idx]], occ[(size_t)b * NN + n]);
}

__global__ __launch_bounds__(256) void weight_kernel(const int* cell_ind, const float* occ,
                                                     const float* counts, float* wts){
  int idx = blockIdx.x * 256 + threadIdx.x;
  int n  = idx & (NN - 1);
  int bg = idx >> 15;
  int b  = bg / NGG;
  float o = occ[(size_t)b * NN + n];
  float cnt = counts[(size_t)bg * HWC + cell_ind[idx]];
  wts[idx] = o / (cnt * o + 1e-6f);
}

// ---------------- BN stats (full pass; layer-0 sm only) ----------------
__global__ __launch_bounds__(256) void bnstats_kernel(const float* tok, const float* gamma,
                                                      const float* beta, float* sOut, float* tOut){
  int c = blockIdx.x;
  int t = threadIdx.x;
  float s = 0.f, sq = 0.f;
  for(int b = 0; b < BB; b++){
    const float4* p = (const float4*)(tok + ((size_t)b * CC + c) * NN);
    for(int i = t; i < NN / 4; i += 256){
      float4 v = p[i];
      s  += v.x + v.y + v.z + v.w;
      sq += v.x * v.x + v.y * v.y + v.z * v.z + v.w * v.w;
    }
  }
  __shared__ float rs[256], rq[256];
  rs[t] = s; rq[t] = sq;
  __syncthreads();
  for(int off = 128; off > 0; off >>= 1){
    if(t < off){ rs[t] += rs[t + off]; rq[t] += rq[t + off]; }
    __syncthreads();
  }
  if(t == 0){
    float m    = rs[0] / (float)(BB * NN);
    float var  = rq[0] / (float)(BB * NN) - m * m;
    float rstd = rsqrtf(var + 1e-5f);
    float g = gamma[c];
    sOut[c] = rstd * g;
    tOut[c] = beta[c] - m * rstd * g;
  }
}

// ---------------- finalize slot partials -> scale/bias, re-zero slots ----------------
__global__ __launch_bounds__(256) void finalize_kernel(float* momP, const float* gamma, const float* beta,
                                                       float* sOut, float* tOut){
  int c = threadIdx.x;
  float s = 0.f, q = 0.f;
  for(int sl = 0; sl < NSLOT; sl++){
    s += momP[sl * 512 + c];
    q += momP[sl * 512 + 256 + c];
  }
  const float inv = 1.f / (float)(BB * NN);
  float m   = s * inv;
  float var = q * inv - m * m;
  float rstd = rsqrtf(var + 1e-5f);
  float g = gamma[c];
  sOut[c] = rstd * g;
  tOut[c] = beta[c] - m * rstd * g;
  for(int i = c; i < NSLOT * 512; i += 256) momP[i] = 0.f;
}

// ---------------- scatter (normalize + weight + atomic into grid) ----------------
__global__ __launch_bounds__(256) void scatter_kernel(const float* tok, const int* cell_ind,
                                                      const float* wts, const float* sA, const float* tA,
                                                      float* gridA, int g){
  int blk = blockIdx.x;                 // B*N/64
  int b   = blk >> 9;
  int n0  = (blk & 511) << 6;
  int t   = threadIdx.x;
  __shared__ float lds[256 * 65];
  __shared__ int   cellL[64];
  __shared__ float wL[64];
  if(t < 64){
    cellL[t] = cell_ind[((size_t)b * NGG + g) * NN + n0 + t];
    wL[t]    = wts[((size_t)b * NGG + g) * NN + n0 + t];
  }
  // stage + normalize: lds[c][p], p = point within 64
  int pf = (t & 15) * 4;
  for(int i = 0; i < 16; i++){
    int c = (t >> 4) + 16 * i;
    float s  = sA[c];
    float tt = tA[c];
    float4 v = *(const float4*)(tok + ((size_t)b * CC + c) * NN + n0 + pf);
    lds[c * 65 + pf + 0] = v.x * s + tt;
    lds[c * 65 + pf + 1] = v.y * s + tt;
    lds[c * 65 + pf + 2] = v.z * s + tt;
    lds[c * 65 + pf + 3] = v.w * s + tt;
  }
  __syncthreads();
  for(int p = 0; p < 64; p++){
    int   cell = cellL[p];
    float wp   = wL[p];
    atomicAdd(&gridA[((size_t)b * HWC + cell) * CC + t], lds[t * 65 + p] * wp);
  }
}

// ---------------- fused dwconv1 + relu + dwconv2, register rolling window, no LDS ----------------
__global__ __launch_bounds__(256) void conv_kernel(const float* __restrict__ gridA,
                                                   const float* __restrict__ k1, const float* __restrict__ b1,
                                                   const float* __restrict__ k2, const float* __restrict__ b2,
                                                   short* __restrict__ gridB){
  int bi = blockIdx.x;                  // b*1024 + ty*32 + tx
  int tx = bi & 31;
  int ty = (bi >> 5) & 31;
  int b  = bi >> 10;
  int c  = threadIdx.x;                 // 0..255 : one channel per thread
  int x0 = tx * 8, y0 = ty * 8;

  float w1r[9], w2r[9];
  #pragma unroll
  for(int i = 0; i < 9; i++){
    w1r[i] = k1[(size_t)c * 9 + i];
    w2r[i] = k2[(size_t)c * 9 + i];
  }
  float bb1 = b1[c], bb2 = b2[c];

  const float* gb = gridA + (size_t)b * HWC * CC + c;
  short*       ob = gridB + (size_t)b * HWC * CC + c;

  float in[3][12];                      // rolling 3 input rows (12 wide, halo 2)
  float mid[3][10];                     // rolling 3 mid rows (10 wide, halo 1)

  auto loadrow = [&](int slot, int yy){
    #pragma unroll
    for(int j = 0; j < 12; j++){
      int xx = x0 - 2 + j;
      float v = 0.f;
      if(yy >= 0 && yy < HH && xx >= 0 && xx < WW)
        v = gb[((size_t)yy * WW + xx) * CC];
      in[slot][j] = v;
    }
  };
  loadrow(0, y0 - 2);
  loadrow(1, y0 - 1);

  #pragma unroll
  for(int r = 0; r < 10; r++){
    loadrow((r + 2) % 3, y0 + r);
    int ym = y0 - 1 + r;
    int s0 = r % 3, s1 = (r + 1) % 3, s2 = (r + 2) % 3;
    bool yok = (ym >= 0) && (ym < HH);
    #pragma unroll
    for(int mx = 0; mx < 10; mx++){
      int xg = x0 - 1 + mx;
      float a = bb1;
      #pragma unroll
      for(int kx = 0; kx < 3; kx++){
        a += in[s0][mx + kx] * w1r[0 * 3 + kx];
        a += in[s1][mx + kx] * w1r[1 * 3 + kx];
        a += in[s2][mx + kx] * w1r[2 * 3 + kx];
      }
      float v = fmaxf(a, 0.f);
      if(!yok || xg < 0 || xg >= WW) v = 0.f;   // conv2 SAME-pads with 0 outside image
      mid[r % 3][mx] = v;
    }
    if(r >= 2){
      int oy = r - 2;
      int m0 = (r - 2) % 3, m1 = (r - 1) % 3, m2 = r % 3;
      #pragma unroll
      for(int ox = 0; ox < 8; ox++){
        float a = bb2;
        #pragma unroll
        for(int kx = 0; kx < 3; kx++){
          a += mid[m0][ox + kx] * w2r[0 * 3 + kx];
          a += mid[m1][ox + kx] * w2r[1 * 3 + kx];
          a += mid[m2][ox + kx] * w2r[2 * 3 + kx];
        }
        ob[((size_t)(y0 + oy) * WW + (x0 + ox)) * CC] = f2bf(a);
      }
    }
  }
}

// ---------------- gather + residual (+ cm BN moment accumulation, slot-spread) ----------------
__global__ __launch_bounds__(256) void gather_kernel(const float* tokIn, float* tokOut, const short* gridB,
                                                     const int* cell_ind, const float* occ,
                                                     const float* smScale, int g, float* cmMomP){
  int blk = blockIdx.x;
  int b   = blk >> 9;
  int n0  = (blk & 511) << 6;
  int t   = threadIdx.x;
  float* momSlot = cmMomP + (size_t)(blk & (NSLOT - 1)) * 512;
  __shared__ float lds[256 * 65];
  __shared__ int   cellL[64];
  __shared__ float occL[64];
  if(t < 64){
    cellL[t] = cell_ind[((size_t)b * NGG + g) * NN + n0 + t];
    occL[t]  = occ[(size_t)b * NN + n0 + t];
  }
  __syncthreads();
  int half = t >> 7;
  int ch   = (t & 127) * 2;
  for(int it = 0; it < 32; it++){
    int p = it * 2 + half;
    int cell = cellL[p];
    uint32_t u = *(const uint32_t*)&gridB[((size_t)b * HWC + cell) * CC + ch];
    lds[ch * 65 + p]       = bf2f((short)(u & 0xffff));
    lds[(ch + 1) * 65 + p] = bf2f((short)(u >> 16));
  }
  __syncthreads();
  int pf = (t & 15) * 4;
  int j  = t & 15;
  for(int i = 0; i < 16; i++){
    int c = (t >> 4) + 16 * i;
    float sc = smScale[c];
    size_t addr = ((size_t)b * CC + c) * NN + n0 + pf;
    float4 tv = *(const float4*)(tokIn + addr);
    float4 o;
    o.x = tv.x + sc * (occL[pf + 0] * lds[c * 65 + pf + 0]);
    o.y = tv.y + sc * (occL[pf + 1] * lds[c * 65 + pf + 1]);
    o.z = tv.z + sc * (occL[pf + 2] * lds[c * 65 + pf + 2]);
    o.w = tv.w + sc * (occL[pf + 3] * lds[c * 65 + pf + 3]);
    *(float4*)(tokOut + addr) = o;
    // cm BN moments: reduce over the 16 lanes sharing channel c
    float s1 = o.x + o.y + o.z + o.w;
    float s2 = o.x * o.x + o.y * o.y + o.z * o.z + o.w * o.w;
    s1 += __shfl_xor(s1, 1);  s2 += __shfl_xor(s2, 1);
    s1 += __shfl_xor(s1, 2);  s2 += __shfl_xor(s2, 2);
    s1 += __shfl_xor(s1, 4);  s2 += __shfl_xor(s2, 4);
    s1 += __shfl_xor(s1, 8);  s2 += __shfl_xor(s2, 8);
    if(j == i){
      atomicAdd(&momSlot[c], s1);
      atomicAdd(&momSlot[256 + c], s2);
    }
  }
}

// ---------------- fold BN into W1/b1, convert W2 ----------------
__global__ __launch_bounds__(256) void fold_kernel(const float* w1, const float* bias1, const float* w2,
                                                   const float* sB, const float* tB,
                                                   short* W1f, short* W2f, float* b1f){
  int o = blockIdx.x;
  int t = threadIdx.x;
  float w = w1[(size_t)o * CC + t];
  W1f[o * CC + t] = f2bf(w * sB[t]);
  W2f[o * CC + t] = f2bf(w2[(size_t)o * CC + t]);
  __shared__ float red[256];
  red[t] = w * tB[t];
  __syncthreads();
  for(int off = 128; off > 0; off >>= 1){
    if(t < off) red[t] += red[t + off];
    __syncthreads();
  }
  if(t == 0) b1f[o] = bias1[o] + red[0];
}

// ---------------- fused MLP (+ sm BN moment accumulation, slot-spread) ----------------
__global__ __launch_bounds__(256) void mlp_kernel(float* tok, const short* W1f, const float* b1f,
                                                  const short* W2f, const float* b2, const float* sc2,
                                                  float* smMomP){
  int blk = blockIdx.x;                  // B * N/64
  int b   = blk >> 9;
  int n0  = (blk & 511) << 6;
  int t   = threadIdx.x;
  int w   = t >> 6;
  int l   = t & 63;
  float* momSlot = smMomP + (size_t)(blk & (NSLOT - 1)) * 512;
  __shared__ short lds[64 * 256];        // swizzled; X tile, then reused for H tile
  float* tb = tok + (size_t)b * CC * NN;

  // stage X tile (64 tokens x 256 channels), transpose 4x4 in regs
  {
    int nb = t & 15;
    int cbq = t >> 4;
    for(int i = 0; i < 4; i++){
      int c0 = cbq * 4 + 64 * i;
      float4 v0 = *(const float4*)(tb + (size_t)(c0 + 0) * NN + n0 + nb * 4);
      float4 v1 = *(const float4*)(tb + (size_t)(c0 + 1) * NN + n0 + nb * 4);
      float4 v2 = *(const float4*)(tb + (size_t)(c0 + 2) * NN + n0 + nb * 4);
      float4 v3 = *(const float4*)(tb + (size_t)(c0 + 3) * NN + n0 + nb * 4);
      short4v s0 = { f2bf(v0.x), f2bf(v1.x), f2bf(v2.x), f2bf(v3.x) };
      short4v s1 = { f2bf(v0.y), f2bf(v1.y), f2bf(v2.y), f2bf(v3.y) };
      short4v s2 = { f2bf(v0.z), f2bf(v1.z), f2bf(v2.z), f2bf(v3.z) };
      short4v s3 = { f2bf(v0.w), f2bf(v1.w), f2bf(v2.w), f2bf(v3.w) };
      *(short4v*)&lds[LXW(nb * 4 + 0, c0)] = s0;
      *(short4v*)&lds[LXW(nb * 4 + 1, c0)] = s1;
      *(short4v*)&lds[LXW(nb * 4 + 2, c0)] = s2;
      *(short4v*)&lds[LXW(nb * 4 + 3, c0)] = s3;
    }
  }
  __syncthreads();

  int ob = w * 64;
  int lr = l & 15;
  int lq = l >> 4;

  f32x4 acc[4][4];
  for(int m = 0; m < 4; m++)
    for(int nf = 0; nf < 4; nf++)
      acc[m][nf] = (f32x4){0.f, 0.f, 0.f, 0.f};
  for(int kk = 0; kk < 8; kk++){
    int kb = kk * 32 + lq * 8;
    short8 af[4], bfr[4];
    for(int m = 0; m < 4; m++)
      af[m] = *(const short8*)&W1f[(size_t)(ob + m * 16 + lr) * CC + kb];
    for(int nf = 0; nf < 4; nf++)
      bfr[nf] = *(const short8*)&lds[LXW(nf * 16 + lr, kb)];
    for(int m = 0; m < 4; m++)
      for(int nf = 0; nf < 4; nf++)
        acc[m][nf] = __builtin_amdgcn_mfma_f32_16x16x32_bf16(af[m], bfr[nf], acc[m][nf], 0, 0, 0);
  }
  __syncthreads();                       // all X reads done before H overwrites the buffer

  // epilogue 1: + b1', relu, bf16 -> lds (H tile, [n][o] swizzled)
  for(int m = 0; m < 4; m++){
    int o0 = ob + m * 16 + lq * 4;
    float bb0 = b1f[o0], bb1 = b1f[o0 + 1], bb2 = b1f[o0 + 2], bb3 = b1f[o0 + 3];
    for(int nf = 0; nf < 4; nf++){
      int n = nf * 16 + lr;
      short4v hv = { f2bf(fmaxf(acc[m][nf][0] + bb0, 0.f)),
                     f2bf(fmaxf(acc[m][nf][1] + bb1, 0.f)),
                     f2bf(fmaxf(acc[m][nf][2] + bb2, 0.f)),
                     f2bf(fmaxf(acc[m][nf][3] + bb3, 0.f)) };
      *(short4v*)&lds[LXW(n, o0)] = hv;
    }
  }
  __syncthreads();

  f32x4 acc2[4][4];
  for(int m = 0; m < 4; m++)
    for(int nf = 0; nf < 4; nf++)
      acc2[m][nf] = (f32x4){0.f, 0.f, 0.f, 0.f};
  for(int kk = 0; kk < 8; kk++){
    int kb = kk * 32 + lq * 8;
    short8 af[4], bfr[4];
    for(int m = 0; m < 4; m++)
      af[m] = *(const short8*)&W2f[(size_t)(ob + m * 16 + lr) * CC + kb];
    for(int nf = 0; nf < 4; nf++)
      bfr[nf] = *(const short8*)&lds[LXW(nf * 16 + lr, kb)];
    for(int m = 0; m < 4; m++)
      for(int nf = 0; nf < 4; nf++)
        acc2[m][nf] = __builtin_amdgcn_mfma_f32_16x16x32_bf16(af[m], bfr[nf], acc2[m][nf], 0, 0, 0);
  }
  // epilogue 2: tok += sc2*(acc2 + b2); accumulate sm BN moments of the values written
  for(int m = 0; m < 4; m++){
    int o0 = ob + m * 16 + lq * 4;
    for(int r = 0; r < 4; r++){
      int o = o0 + r;
      float s  = sc2[o];
      float bb = b2[o];
      float s1 = 0.f, s2 = 0.f;
      for(int nf = 0; nf < 4; nf++){
        int n = nf * 16 + lr;
        size_t addr = (size_t)o * NN + n0 + n;
        float v = tb[addr] + s * (acc2[m][nf][r] + bb);
        tb[addr] = v;
        s1 += v;
        s2 += v * v;
      }
      s1 += __shfl_xor(s1, 1);  s2 += __shfl_xor(s2, 1);
      s1 += __shfl_xor(s1, 2);  s2 += __shfl_xor(s2, 2);
      s1 += __shfl_xor(s1, 4);  s2 += __shfl_xor(s2, 4);
      s1 += __shfl_xor(s1, 8);  s2 += __shfl_xor(s2, 8);
      if(lr == m * 4 + r){
        atomicAdd(&momSlot[o], s1);
        atomicAdd(&momSlot[256 + o], s2);
      }
    }
  }
}

extern "C" void kernel_launch(void* const* d_in, const int* in_sizes, int n_in,
                              void* d_out, int out_size, void* d_ws, size_t ws_size,
                              hipStream_t stream) {
  const float* tokens   = (const float*)d_in[0];
  const int*   cell_ind = (const int*)d_in[1];
  const float* occ      = (const float*)d_in[2];
  const float* cm_gamma = (const float*)d_in[3];
  const float* cm_beta  = (const float*)d_in[4];
  const float* cm_w1    = (const float*)d_in[5];
  const float* cm_b1    = (const float*)d_in[6];
  const float* cm_w2    = (const float*)d_in[7];
  const float* cm_b2    = (const float*)d_in[8];
  const float* cm_scale = (const float*)d_in[9];
  const float* sm_gamma = (const float*)d_in[10];
  const float* sm_beta  = (const float*)d_in[11];
  const float* sm_k1    = (const float*)d_in[12];
  const float* sm_b1    = (const float*)d_in[13];
  const float* sm_k2    = (const float*)d_in[14];
  const float* sm_b2    = (const float*)d_in[15];
  const float* sm_scale = (const float*)d_in[16];
  float* out = (float*)d_out;
  (void)in_sizes; (void)n_in; (void)out_size; (void)ws_size;

  char* ws = (char*)d_ws;
  size_t off = 0;
  auto carve = [&](size_t bytes) -> void* {
    void* p = ws + off;
    off = (off + bytes + 255) & ~(size_t)255;
    return p;
  };
  float* counts = (float*)carve((size_t)BB * NGG * HWC * 4);   // 1.5 MB
  float* smMomP = (float*)carve((size_t)NSLOT * 512 * 4);      // 128 KB, contiguous with counts
  float* cmMomP = (float*)carve((size_t)NSLOT * 512 * 4);      // 128 KB
  float* wts    = (float*)carve((size_t)BB * NGG * NN * 4);
  float* sA  = (float*)carve(CC * 4);
  float* tA  = (float*)carve(CC * 4);
  float* sB  = (float*)carve(CC * 4);
  float* tB  = (float*)carve(CC * 4);
  float* b1f = (float*)carve(CC * 4);
  short* W1f = (short*)carve((size_t)CC * CC * 2);
  short* W2f = (short*)carve((size_t)CC * CC * 2);
  float* gridA = (float*)carve((size_t)BB * HWC * CC * 4);
  short* gridB = (short*)carve((size_t)BB * HWC * CC * 2);

  // zero counts + both slot-partial buffers in one memset (carved contiguously)
  hipMemsetAsync(counts, 0, (size_t)BB * NGG * HWC * 4 + 2 * (size_t)NSLOT * 512 * 4, stream);
  count_kernel<<<BB * NGG * NN / 256, 256, 0, stream>>>(cell_ind, occ, counts);
  weight_kernel<<<BB * NGG * NN / 256, 256, 0, stream>>>(cell_ind, occ, counts, wts);

  const float* tokCur = tokens;
  for(int d = 0; d < DD; d++){
    int g = d % NGG;
    if(d == 0)
      bnstats_kernel<<<CC, 256, 0, stream>>>(tokCur, sm_gamma, sm_beta, sA, tA);
    else
      finalize_kernel<<<1, 256, 0, stream>>>(smMomP, sm_gamma + d * CC, sm_beta + d * CC, sA, tA);
    hipMemsetAsync(gridA, 0, (size_t)BB * HWC * CC * 4, stream);
    scatter_kernel<<<BB * NN / 64, 256, 0, stream>>>(tokCur, cell_ind, wts, sA, tA, gridA, g);
    conv_kernel<<<BB * 32 * 32, 256, 0, stream>>>(gridA, sm_k1 + (size_t)d * CC * 9, sm_b1 + d * CC,
                                                  sm_k2 + (size_t)d * CC * 9, sm_b2 + d * CC, gridB);
    gather_kernel<<<BB * NN / 64, 256, 0, stream>>>(tokCur, out, gridB, cell_ind, occ,
                                                    sm_scale + d * CC, g, cmMomP);
    finalize_kernel<<<1, 256, 0, stream>>>(cmMomP, cm_gamma + d * CC, cm_beta + d * CC, sB, tB);
    fold_kernel<<<CC, 256, 0, stream>>>(cm_w1 + (size_t)d * CC * CC, cm_b1 + d * CC,
                                        cm_w2 + (size_t)d * CC * CC, sB, tB, W1f, W2f, b1f);
    mlp_kernel<<<BB * NN / 64, 256, 0, stream>>>(out, W1f, b1f, W2f, cm_b2 + d * CC,
                                                 cm_scale + d * CC, smMomP);
    tokCur = out;
  }
}